// Round 1
// 270.150 us; speedup vs baseline: 1.1619x; 1.1619x over previous
//
#include <hip/hip_runtime.h>
#include <hip/hip_bf16.h>
#include <math.h>

#define Tn   8192
#define Hn   1024
#define En   8
#define DFFn 4096

typedef __attribute__((ext_vector_type(8))) short bf16x8;  // 8 bf16 = 4 VGPRs
typedef __attribute__((ext_vector_type(4))) float f32x4;

static __device__ inline unsigned short f2bf(float f) {
    __hip_bfloat16 h = __float2bfloat16(f);
    return __builtin_bit_cast(unsigned short, h);
}

// ---------------- prep: gate + x->bf16, W1 transpose, W2 transpose --------
// blocks [0,1024): gate scores + top-2 softmax sum + x->bf16 cast
// blocks [1024,5120): W1 [1024x4096] -> W1t [4096][1024] bf16 (32x32 tiles)
// blocks [5120,9216): W2 [4096][1024] -> W2t [1024][4096] bf16 (32x32 tiles)
__global__ __launch_bounds__(256) void prep(
    const float* __restrict__ W1, unsigned short* __restrict__ W1t,
    const float* __restrict__ W2, unsigned short* __restrict__ W2t,
    const float* __restrict__ x, const float* __restrict__ gW,
    const float* __restrict__ gb, unsigned short* __restrict__ xbf,
    float* __restrict__ tokw, float* __restrict__ load_sum,
    int* __restrict__ counts)
{
    __shared__ float smem[8 * 1024 + En];   // gwt[8][1024] | s_load tail
    __shared__ int   s_cnt[En];
    const int tid = threadIdx.x;
    const int id  = blockIdx.x;

    if (id >= 5120) {  // ---- W2 transpose+cast ----
        const int tb = id - 5120;                   // 0..4095
        float* tile = smem;                         // [32][33]
        const int bx = tb & 31, by = tb >> 5;       // n-tile (H/32), k-tile (DFF/32)
        const int n0 = bx * 32, k0 = by * 32;
        const int r  = tid >> 3, c4 = (tid & 7) * 4;
        float4 v = *(const float4*)(W2 + (size_t)(k0 + r) * Hn + n0 + c4);
        tile[(c4 + 0) * 33 + r] = v.x;
        tile[(c4 + 1) * 33 + r] = v.y;
        tile[(c4 + 2) * 33 + r] = v.z;
        tile[(c4 + 3) * 33 + r] = v.w;
        __syncthreads();
        ushort4 pk;
        pk.x = f2bf(tile[r * 33 + c4 + 0]);
        pk.y = f2bf(tile[r * 33 + c4 + 1]);
        pk.z = f2bf(tile[r * 33 + c4 + 2]);
        pk.w = f2bf(tile[r * 33 + c4 + 3]);
        *(ushort4*)(W2t + (size_t)(n0 + r) * DFFn + k0 + c4) = pk;
        return;
    }

    if (id >= 1024) {  // ---- W1 transpose+cast, float4 in / ushort4 out ----
        const int tb = id - 1024;
        float* tile = smem;                         // [32][33]
        const int bx = tb & 127, by = tb >> 7;      // n-tile, k-tile
        const int n0 = bx * 32, k0 = by * 32;
        const int r  = tid >> 3, c4 = (tid & 7) * 4;
        float4 v = *(const float4*)(W1 + (size_t)(k0 + r) * DFFn + n0 + c4);
        tile[(c4 + 0) * 33 + r] = v.x;
        tile[(c4 + 1) * 33 + r] = v.y;
        tile[(c4 + 2) * 33 + r] = v.z;
        tile[(c4 + 3) * 33 + r] = v.w;
        __syncthreads();
        ushort4 pk;
        pk.x = f2bf(tile[r * 33 + c4 + 0]);
        pk.y = f2bf(tile[r * 33 + c4 + 1]);
        pk.z = f2bf(tile[r * 33 + c4 + 2]);
        pk.w = f2bf(tile[r * 33 + c4 + 3]);
        *(ushort4*)(W1t + (size_t)(n0 + r) * Hn + k0 + c4) = pk;
        return;
    }

    // ---- gate + x cast; gW staged into LDS transposed [E][H] ----
    float* gwt    = smem;                // 32 KB
    float* s_load = smem + 8 * 1024;
    if (tid < En) { s_load[tid] = 0.f; s_cnt[tid] = 0; }
    #pragma unroll
    for (int i = 0; i < 32; ++i) {       // 8192 floats, coalesced read
        int f = tid + i * 256;
        gwt[(f & 7) * 1024 + (f >> 3)] = gW[f];
    }
    __syncthreads();

    const int lane = tid & 63;
    const int wv   = tid >> 6;

    for (int tok = id * 4 + wv; tok < Tn; tok += 4096) {   // 2 toks/wave
        const float4* xr = (const float4*)(x + (size_t)tok * Hn);
        float acc[8] = {0.f,0.f,0.f,0.f,0.f,0.f,0.f,0.f};
        #pragma unroll
        for (int j = 0; j < Hn / 256; ++j) {           // 4 iterations
            int h4 = j * 64 + lane;
            float4 xv = xr[h4];
            ushort4 pk;
            pk.x = f2bf(xv.x); pk.y = f2bf(xv.y);
            pk.z = f2bf(xv.z); pk.w = f2bf(xv.w);
            ((ushort4*)xbf)[(size_t)tok * (Hn / 4) + h4] = pk;
            #pragma unroll
            for (int e = 0; e < 8; ++e) {
                const float4 w = *(const float4*)(gwt + e * 1024 + h4 * 4);
                acc[e] += xv.x * w.x + xv.y * w.y + xv.z * w.z + xv.w * w.w;
            }
        }
        #pragma unroll
        for (int e = 0; e < 8; ++e) {
            float v = acc[e];
            #pragma unroll
            for (int off = 32; off > 0; off >>= 1) v += __shfl_xor(v, off, 64);
            acc[e] = v + gb[e];
        }
        if (lane == 0) {
            #pragma unroll
            for (int e = 0; e < 8; ++e) atomicAdd(&s_load[e], acc[e]);
            int i1 = 0; float v1 = acc[0];
            #pragma unroll
            for (int e = 1; e < 8; ++e) if (acc[e] > v1) { v1 = acc[e]; i1 = e; }
            int i2 = -1; float v2 = -3.0e38f;
            #pragma unroll
            for (int e = 0; e < 8; ++e) if (e != i1 && acc[e] > v2) { v2 = acc[e]; i2 = e; }
            atomicAdd(&s_cnt[i1], 1);
            atomicAdd(&s_cnt[i2], 1);
            float e2 = __expf(v2 - v1);
            float t  = 1.0f + e2;
            tokw[tok] = 1.0f / t + e2 / t;   // softmax(top2).sum()
        }
    }
    __syncthreads();
    if (tid < En) {
        atomicAdd(&load_sum[tid], s_load[tid]);
        atomicAdd(&counts[tid],   s_cnt[tid]);
    }
}

// =================== 8-phase 256-wide GEMM (HK-style schedule) ============
// C = epilogue(A @ Bt^T + bias); A:[M][K] bf16 row-major, Bt:[N][K] bf16.
// BM=256, BK=64, 512 thr = 8 waves (WM x WN).  Double-buffered LDS,
// global_load_lds width-16 staging, counted vmcnt (never 0 in loop),
// XOR slot-swizzle (slot = chunk ^ (row&7)) applied on the GLOBAL source
// (linear LDS dest) and on the ds_read_b128 address -> conflict-free.
//
// Per phase: {ds_read quadrant frags | stage 2 units} ; s_barrier ;
//            lgkmcnt(0) ; setprio(1) MFMA-quadrant setprio(0) ;
//            [vmcnt(6|4) at end of P3/P7] ; s_barrier.
// Stage schedule is retire-ordered: a unit is staged only in a phase
// strictly after its last ds_read (barrier-separated), and the vmcnt at
// P3/P7 guarantees the tile consumed by the next 4-phase group has fully
// landed in LDS before any wave reads it.
//   G0 (BN=256, WM=2,WN=4): A units {0,2} retire P0, B P1, A {1,3} P2.
//     stages: P0 buf1.A{1,3}(t1)  P1 buf0.A{0,2}(t+2)  P2 buf0.B{0,1}
//             P3 buf0.B{2,3}      P4 buf0.A{1,3}       P5 buf1.A{0,2}(t+3)
//             P6 buf1.B{0,1}      P7 buf1.B{2,3};  vmcnt(6) at P3/P7.
//   G1 (BN=128, WM=4,WN=2): A retires P2, B retires P1.
//     stages: P0 buf1.A{2,3}(t1)  P2 buf0.B{0,1}(t+2)  P3 buf0.A{0,1}
//             P4 buf0.A{2,3}      P6 buf1.B{0,1}(t+3)  P7 buf1.A{0,1};
//             vmcnt(4) at P3/P7.
// EPI==0: C = bf16(gelu(v+bias)); extra block id==nblk writes aux/counts.
// EPI==1: C = fp32((v+bias) * tokw[row]).

static __device__ inline bf16x8 ldsfrag(const char* base, int row, int chunk) {
    return *(const bf16x8*)(base + row * 128 + (((chunk) ^ (row & 7)) << 4));
}

template<int BN, int WM, int WN, int EPI>
__global__ __launch_bounds__(512, 2) void gemm8(
    const __hip_bfloat16* __restrict__ A,
    const __hip_bfloat16* __restrict__ Bt,
    const float* __restrict__ bias,
    const float* __restrict__ tokw,
    void* __restrict__ C, int N, int K, int nx,
    const float* __restrict__ load_sum, const int* __restrict__ counts,
    float* __restrict__ out_tail, int nblk)
{
    constexpr int BM = 256;
    constexpr int MR = (BM / WM) / 16;        // 8 (G0) or 4 (G1)
    constexpr int NR = (BN / WN) / 16;        // 4
    constexpr int AU = BM / 64;               // 4 stage units (8 KB each)
    constexpr int BU = BN / 64;               // 4 (G0) or 2 (G1)
    constexpr int ABYTES = BM * 64 * 2;       // 32 KB
    constexpr int BBYTES = BN * 64 * 2;       // 32/16 KB
    constexpr int TILEB  = ABYTES + BBYTES;   // per K-tile buffer

    extern __shared__ char lds[];

    const int tid = threadIdx.x;
    const int id  = blockIdx.x;

    if (EPI == 0 && id >= nblk) {   // ---- aux-loss / counts tail block ----
        if (tid == 0) {
            float aux = 0.f;
            #pragma unroll
            for (int e = 0; e < En; ++e) {
                float m = load_sum[e] * (1.0f / (float)Tn);
                aux += m * m;
            }
            out_tail[0] = aux;
            #pragma unroll
            for (int e = 0; e < En; ++e) out_tail[1 + e] = (float)counts[e];
        }
        return;
    }

    // bijective XCD swizzle (nblk % 8 == 0 for both instantiations)
    int wg = id;
    { int xcd = wg & 7, idx = wg >> 3; wg = xcd * (nblk >> 3) + idx; }
    const int by = wg / nx, bx = wg % nx;
    const int m0 = by * BM, n0 = bx * BN;

    const int lane = tid & 63;
    const int wid  = tid >> 6;
    const int wn   = wid % WN;
    const int wm   = wid / WN;
    const int wrow = wm * (BM / WM);
    const int wcol = wn * (BN / WN);
    const int fr   = lane & 15;
    const int fq   = lane >> 4;

    // staging map: thread t covers LDS (row=t>>3, slot=t&7) of one unit;
    // source k-chunk pre-swizzled so ds_read applies the same XOR.
    const int sr = tid >> 3;                 // 0..63
    const int sc = (tid & 7) ^ (sr & 7);     // global k-chunk (8 bf16)
    unsigned aOff[AU], bOff[BU];
    #pragma unroll
    for (int u = 0; u < AU; ++u)
        aOff[u] = (unsigned)((m0 + u * 64 + sr) * K + sc * 8);
    #pragma unroll
    for (int u = 0; u < BU; ++u)
        bOff[u] = (unsigned)((n0 + u * 64 + sr) * K + sc * 8);

#define STA(b, u, kt) __builtin_amdgcn_global_load_lds( \
    (const __attribute__((address_space(1))) void*)(A + aOff[u] + (unsigned)(kt) * 64u), \
    (__attribute__((address_space(3))) void*)(lds + (b) * TILEB + (u) * 8192 + tid * 16), 16, 0, 0)
#define STB(b, u, kt) __builtin_amdgcn_global_load_lds( \
    (const __attribute__((address_space(1))) void*)(Bt + bOff[u] + (unsigned)(kt) * 64u), \
    (__attribute__((address_space(3))) void*)(lds + (b) * TILEB + ABYTES + (u) * 8192 + tid * 16), 16, 0, 0)

    bf16x8 af[MR / 2][2];
    bf16x8 bfr[4][2];
    f32x4  acc[MR][NR];
    const f32x4 zero = {0.f, 0.f, 0.f, 0.f};
    #pragma unroll
    for (int i = 0; i < MR; ++i)
        #pragma unroll
        for (int j = 0; j < NR; ++j) acc[i][j] = zero;

#define RDA(b, half) do { _Pragma("unroll") \
    for (int m_ = 0; m_ < MR / 2; ++m_) { _Pragma("unroll") \
        for (int ks_ = 0; ks_ < 2; ++ks_) \
            af[m_][ks_] = ldsfrag(lds + (b) * TILEB, \
                wrow + ((half) * (MR / 2) + m_) * 16 + fr, ks_ * 4 + fq); } } while (0)

#define RDB(b, half) do { _Pragma("unroll") \
    for (int n_ = 0; n_ < 2; ++n_) { _Pragma("unroll") \
        for (int ks_ = 0; ks_ < 2; ++ks_) \
            bfr[(half) * 2 + n_][ks_] = ldsfrag(lds + (b) * TILEB + ABYTES, \
                wcol + ((half) * 2 + n_) * 16 + fr, ks_ * 4 + fq); } } while (0)

#define MFMAQ(hm, hn) do { \
    __builtin_amdgcn_s_setprio(1); \
    _Pragma("unroll") \
    for (int m_ = 0; m_ < MR / 2; ++m_) { _Pragma("unroll") \
        for (int n_ = 0; n_ < 2; ++n_) { _Pragma("unroll") \
            for (int ks_ = 0; ks_ < 2; ++ks_) \
                acc[(hm) * (MR / 2) + m_][(hn) * 2 + n_] = \
                    __builtin_amdgcn_mfma_f32_16x16x32_bf16( \
                        af[m_][ks_], bfr[(hn) * 2 + n_][ks_], \
                        acc[(hm) * (MR / 2) + m_][(hn) * 2 + n_], 0, 0, 0); } } \
    __builtin_amdgcn_s_setprio(0); } while (0)

#define MIDSYNC do { \
    __builtin_amdgcn_sched_barrier(0); \
    __builtin_amdgcn_s_barrier(); \
    asm volatile("s_waitcnt lgkmcnt(0)" ::: "memory"); \
    __builtin_amdgcn_sched_barrier(0); } while (0)

#define ENDBAR do { \
    __builtin_amdgcn_sched_barrier(0); \
    __builtin_amdgcn_s_barrier(); \
    __builtin_amdgcn_sched_barrier(0); } while (0)

#define DRAIN do { \
    if constexpr (WM == 2) asm volatile("s_waitcnt vmcnt(6)" ::: "memory"); \
    else                   asm volatile("s_waitcnt vmcnt(4)" ::: "memory"); \
    __builtin_amdgcn_sched_barrier(0); } while (0)

    const int KT = K >> 6;   // K-tiles of 64

    // ---- prologue: tile0 complete + tile1 minus the units P0 will stage
    if constexpr (WM == 2) {
        STA(0,0,0); STA(0,1,0); STA(0,2,0); STA(0,3,0);
        STB(0,0,0); STB(0,1,0); STB(0,2,0); STB(0,3,0);
        STA(1,0,1); STA(1,2,1);
        STB(1,0,1); STB(1,1,1); STB(1,2,1); STB(1,3,1);
        asm volatile("s_waitcnt vmcnt(6)" ::: "memory");
    } else {
        STA(0,0,0); STA(0,1,0); STA(0,2,0); STA(0,3,0);
        STB(0,0,0); STB(0,1,0);
        STA(1,0,1); STA(1,1,1);
        STB(1,0,1); STB(1,1,1);
        asm volatile("s_waitcnt vmcnt(4)" ::: "memory");
    }
    __builtin_amdgcn_sched_barrier(0);
    __builtin_amdgcn_s_barrier();
    __builtin_amdgcn_sched_barrier(0);

    for (int i = 0; i < (KT >> 1); ++i) {
        const int t1 = 2 * i + 1;
        const int c2 = (2 * i + 2 < KT) ? 2 * i + 2 : KT - 1;
        const int c3 = (2 * i + 3 < KT) ? 2 * i + 3 : KT - 1;

        // ---- P0: compute tile 2i quadrant (0,0)
        RDA(0, 0); RDB(0, 0);
        if constexpr (WM == 2) { STA(1,1,t1); STA(1,3,t1); }
        else                   { STA(1,2,t1); STA(1,3,t1); }
        MIDSYNC; MFMAQ(0, 0); ENDBAR;
        // ---- P1: quadrant (0,1)
        RDB(0, 1);
        if constexpr (WM == 2) { STA(0,0,c2); STA(0,2,c2); }
        MIDSYNC; MFMAQ(0, 1); ENDBAR;
        // ---- P2: quadrant (1,0)
        RDA(0, 1);
        STB(0,0,c2); STB(0,1,c2);
        MIDSYNC; MFMAQ(1, 0); ENDBAR;
        // ---- P3: quadrant (1,1) ; drain so tile 2i+1 is fully in LDS
        if constexpr (WM == 2) { STB(0,2,c2); STB(0,3,c2); }
        else                   { STA(0,0,c2); STA(0,1,c2); }
        MIDSYNC; MFMAQ(1, 1); DRAIN; ENDBAR;
        // ---- P4: compute tile 2i+1 quadrant (0,0)
        RDA(1, 0); RDB(1, 0);
        if constexpr (WM == 2) { STA(0,1,c2); STA(0,3,c2); }
        else                   { STA(0,2,c2); STA(0,3,c2); }
        MIDSYNC; MFMAQ(0, 0); ENDBAR;
        // ---- P5
        RDB(1, 1);
        if constexpr (WM == 2) { STA(1,0,c3); STA(1,2,c3); }
        MIDSYNC; MFMAQ(0, 1); ENDBAR;
        // ---- P6
        RDA(1, 1);
        STB(1,0,c3); STB(1,1,c3);
        MIDSYNC; MFMAQ(1, 0); ENDBAR;
        // ---- P7 ; drain so tile 2i+2 is fully in LDS for next iteration
        if constexpr (WM == 2) { STB(1,2,c3); STB(1,3,c3); }
        else                   { STA(1,0,c3); STA(1,1,c3); }
        MIDSYNC; MFMAQ(1, 1); DRAIN; ENDBAR;
    }

    // ---- epilogue: C/D layout col = lane&15, row = (lane>>4)*4 + reg
    #pragma unroll
    for (int mi = 0; mi < MR; ++mi) {
        #pragma unroll
        for (int ni = 0; ni < NR; ++ni) {
            const int col   = n0 + wcol + ni * 16 + (lane & 15);
            const int rbase = m0 + wrow + mi * 16 + (lane >> 4) * 4;
            const float bv  = bias[col];
            #pragma unroll
            for (int i2 = 0; i2 < 4; ++i2) {
                const int row = rbase + i2;
                float v = acc[mi][ni][i2] + bv;
                if constexpr (EPI == 0) {
                    // gelu tanh-form: v * sigmoid(2u), exp+rcp only (no div)
                    float vv = v * v;
                    float z  = v * __fmaf_rn(vv, -0.07135607f, -1.59576912f);
                    float e  = __expf(z);            // e^{-2u}
                    float g  = v * __builtin_amdgcn_rcpf(1.0f + e);
                    ((__hip_bfloat16*)C)[(size_t)row * N + col] = __float2bfloat16(g);
                } else {
                    ((float*)C)[(size_t)row * N + col] = v * tokw[row];
                }
            }
        }
    }

#undef STA
#undef STB
#undef RDA
#undef RDB
#undef MFMAQ
#undef MIDSYNC
#undef ENDBAR
#undef DRAIN
}

extern "C" void kernel_launch(void* const* d_in, const int* in_sizes, int n_in,
                              void* d_out, int out_size, void* d_ws, size_t ws_size,
                              hipStream_t stream)
{
    const float* x  = (const float*)d_in[0];
    const float* gW = (const float*)d_in[1];
    const float* gb = (const float*)d_in[2];
    const float* W1 = (const float*)d_in[3];
    const float* b1 = (const float*)d_in[4];
    const float* W2 = (const float*)d_in[5];
    const float* b2 = (const float*)d_in[6];
    float* out = (float*)d_out;

    char* ws = (char*)d_ws;
    __hip_bfloat16* xbf = (__hip_bfloat16*)ws;  ws += (size_t)Tn * Hn * 2;     // 16 MB
    __hip_bfloat16* W1t = (__hip_bfloat16*)ws;  ws += (size_t)Hn * DFFn * 2;   //  8 MB
    __hip_bfloat16* W2t = (__hip_bfloat16*)ws;  ws += (size_t)Hn * DFFn * 2;   //  8 MB
    __hip_bfloat16* hdd = (__hip_bfloat16*)ws;  ws += (size_t)Tn * DFFn * 2;   // 64 MB
    float* tokw     = (float*)ws;               ws += (size_t)Tn * 4;          // 32 KB
    float* load_sum = (float*)ws;               ws += En * 4;
    int*   counts   = (int*)ws;                 ws += En * 4;

    static bool attr_done = false;
    if (!attr_done) {
        (void)hipFuncSetAttribute(
            reinterpret_cast<const void*>(&gemm8<256, 2, 4, 0>),
            hipFuncAttributeMaxDynamicSharedMemorySize, 131072);
        (void)hipFuncSetAttribute(
            reinterpret_cast<const void*>(&gemm8<128, 4, 2, 1>),
            hipFuncAttributeMaxDynamicSharedMemorySize, 98304);
        attr_done = true;
    }

    hipMemsetAsync(load_sum, 0, En * 4 * 2, stream);   // load_sum + counts

    prep<<<9216, 256, 0, stream>>>(W1, (unsigned short*)W1t,
                                   W2, (unsigned short*)W2t,
                                   x, gW, gb, (unsigned short*)xbf,
                                   tokw, load_sum, counts);

    // hdd = gelu(x @ W1 + b1): M=8192, N=4096, K=1024; 32x16 = 512 blocks
    gemm8<256, 2, 4, 0><<<513, 512, 131072, stream>>>(
        xbf, W1t, b1, nullptr, hdd, DFFn, Hn, 16,
        load_sum, counts, out + (size_t)Tn * Hn, 512);

    // out = (hdd @ W2 + b2) * tokw: M=8192, N=1024, K=4096; 32x8 = 256 blocks
    gemm8<128, 4, 2, 1><<<256, 512, 98304, stream>>>(
        hdd, W2t, b2, tokw, out, Hn, DFFn, 8,
        nullptr, nullptr, nullptr, 256);
}